// Round 1
// baseline (306.313 us; speedup 1.0000x reference)
//
#include <hip/hip_runtime.h>

// out[s,b,d] = x[s,b,0]*W_xy[d,0] + x[s,b,1]*W_xy[d,1] + b_xy[d]
//            + x[s,b,2]*W_seg[d,0] + b_seg[d] + pe[s,0,d]
// S=256, B=256, D=1024, fp32. Memory-bound: 268 MB output write.

#define S_DIM 256
#define B_DIM 256
#define D_DIM 1024
#define B_PER_BLOCK 32

__global__ __launch_bounds__(256) void pe_fused_kernel(
    const float* __restrict__ x,      // [S,B,3]
    const float* __restrict__ W_xy,   // [D,2]
    const float* __restrict__ b_xy,   // [D]
    const float* __restrict__ W_seg,  // [D,1]
    const float* __restrict__ b_seg,  // [D]
    const float* __restrict__ pe,     // [MAX_LEN,1,D]
    float* __restrict__ out)          // [S,B,D]
{
    const int s  = blockIdx.x;
    const int b0 = blockIdx.y * B_PER_BLOCK;
    const int t  = threadIdx.x;          // 0..255
    const int d  = t << 2;               // 4-wide d slice per thread

    // --- load per-d coefficients once into registers ---
    // W_xy is row-major [D,2]: element (d,j) at W_xy[d*2+j]
    const float4 wA = *(const float4*)(W_xy + (size_t)d * 2);      // d, d+1
    const float4 wB = *(const float4*)(W_xy + (size_t)d * 2 + 4);  // d+2, d+3
    const float c0_0 = wA.x, c1_0 = wA.y;
    const float c0_1 = wA.z, c1_1 = wA.w;
    const float c0_2 = wB.x, c1_2 = wB.y;
    const float c0_3 = wB.z, c1_3 = wB.w;

    const float4 c2  = *(const float4*)(W_seg + d);
    const float4 bxy = *(const float4*)(b_xy + d);
    const float4 bsg = *(const float4*)(b_seg + d);
    const float4 pes = *(const float4*)(pe + (size_t)s * D_DIM + d);

    const float base0 = bxy.x + bsg.x + pes.x;
    const float base1 = bxy.y + bsg.y + pes.y;
    const float base2 = bxy.z + bsg.z + pes.z;
    const float base3 = bxy.w + bsg.w + pes.w;

    // --- loop over batch slice, one coalesced float4 store per iter ---
    #pragma unroll 4
    for (int bi = 0; bi < B_PER_BLOCK; ++bi) {
        const int b = b0 + bi;
        const float* xp = x + ((size_t)s * B_DIM + b) * 3;
        const float x0 = xp[0];
        const float x1 = xp[1];
        const float x2 = xp[2];

        float4 o;
        o.x = fmaf(x0, c0_0, fmaf(x1, c1_0, fmaf(x2, c2.x, base0)));
        o.y = fmaf(x0, c0_1, fmaf(x1, c1_1, fmaf(x2, c2.y, base1)));
        o.z = fmaf(x0, c0_2, fmaf(x1, c1_2, fmaf(x2, c2.z, base2)));
        o.w = fmaf(x0, c0_3, fmaf(x1, c1_3, fmaf(x2, c2.w, base3)));

        *(float4*)(out + (((size_t)s * B_DIM + b) * D_DIM) + d) = o;
    }
}

extern "C" void kernel_launch(void* const* d_in, const int* in_sizes, int n_in,
                              void* d_out, int out_size, void* d_ws, size_t ws_size,
                              hipStream_t stream) {
    const float* x     = (const float*)d_in[0];  // [S,B,3]
    const float* W_xy  = (const float*)d_in[1];  // [D,2]
    const float* b_xy  = (const float*)d_in[2];  // [D]
    const float* W_seg = (const float*)d_in[3];  // [D,1]
    const float* b_seg = (const float*)d_in[4];  // [D]
    const float* pe    = (const float*)d_in[5];  // [MAX_LEN,1,D]
    float* out         = (float*)d_out;          // [S,B,D]

    dim3 grid(S_DIM, B_DIM / B_PER_BLOCK);
    dim3 block(256);
    pe_fused_kernel<<<grid, block, 0, stream>>>(x, W_xy, b_xy, W_seg, b_seg, pe, out);
}

// Round 2
// 264.364 us; speedup vs baseline: 1.1587x; 1.1587x over previous
//
#include <hip/hip_runtime.h>

// out[s,b,d] = x[s,b,0]*W_xy[d,0] + x[s,b,1]*W_xy[d,1] + b_xy[d]
//            + x[s,b,2]*W_seg[d,0] + b_seg[d] + pe[s,0,d]
// S=256, B=256, D=1024, fp32. Memory-bound: 268 MB output write.
// R2: stage x[s, b0:b0+32, :] in LDS once per block so the hot loop has no
// global-load latency; pointer-bump stores; unroll 8.

#define S_DIM 256
#define B_DIM 256
#define D_DIM 1024
#define B_PER_BLOCK 32

__global__ __launch_bounds__(256) void pe_fused_kernel(
    const float* __restrict__ x,      // [S,B,3]
    const float* __restrict__ W_xy,   // [D,2]
    const float* __restrict__ b_xy,   // [D]
    const float* __restrict__ W_seg,  // [D,1]
    const float* __restrict__ b_seg,  // [D]
    const float* __restrict__ pe,     // [MAX_LEN,1,D]
    float* __restrict__ out)          // [S,B,D]
{
    const int s  = blockIdx.x;
    const int b0 = blockIdx.y * B_PER_BLOCK;
    const int t  = threadIdx.x;          // 0..255
    const int d  = t << 2;               // 4-wide d slice per thread

    // --- stage this block's x slice into LDS (32 b-values x 3 floats) ---
    __shared__ float xs[B_PER_BLOCK * 3];
    if (t < B_PER_BLOCK * 3) {
        xs[t] = x[((size_t)s * B_DIM + b0) * 3 + t];
    }

    // --- load per-d coefficients once into registers ---
    const float4 wA = *(const float4*)(W_xy + (size_t)d * 2);      // d, d+1
    const float4 wB = *(const float4*)(W_xy + (size_t)d * 2 + 4);  // d+2, d+3
    const float c0_0 = wA.x, c1_0 = wA.y;
    const float c0_1 = wA.z, c1_1 = wA.w;
    const float c0_2 = wB.x, c1_2 = wB.y;
    const float c0_3 = wB.z, c1_3 = wB.w;

    const float4 c2  = *(const float4*)(W_seg + d);
    const float4 bxy = *(const float4*)(b_xy + d);
    const float4 bsg = *(const float4*)(b_seg + d);
    const float4 pes = *(const float4*)(pe + (size_t)s * D_DIM + d);

    const float base0 = bxy.x + bsg.x + pes.x;
    const float base1 = bxy.y + bsg.y + pes.y;
    const float base2 = bxy.z + bsg.z + pes.z;
    const float base3 = bxy.w + bsg.w + pes.w;

    __syncthreads();

    // --- hot loop: LDS broadcast reads + FMA + one float4 store per iter ---
    float* op = out + ((size_t)s * B_DIM + b0) * D_DIM + d;
    #pragma unroll 8
    for (int bi = 0; bi < B_PER_BLOCK; ++bi, op += D_DIM) {
        const float x0 = xs[bi * 3 + 0];
        const float x1 = xs[bi * 3 + 1];
        const float x2 = xs[bi * 3 + 2];

        float4 o;
        o.x = fmaf(x0, c0_0, fmaf(x1, c1_0, fmaf(x2, c2.x, base0)));
        o.y = fmaf(x0, c0_1, fmaf(x1, c1_1, fmaf(x2, c2.y, base1)));
        o.z = fmaf(x0, c0_2, fmaf(x1, c1_2, fmaf(x2, c2.z, base2)));
        o.w = fmaf(x0, c0_3, fmaf(x1, c1_3, fmaf(x2, c2.w, base3)));

        *(float4*)op = o;
    }
}

extern "C" void kernel_launch(void* const* d_in, const int* in_sizes, int n_in,
                              void* d_out, int out_size, void* d_ws, size_t ws_size,
                              hipStream_t stream) {
    const float* x     = (const float*)d_in[0];  // [S,B,3]
    const float* W_xy  = (const float*)d_in[1];  // [D,2]
    const float* b_xy  = (const float*)d_in[2];  // [D]
    const float* W_seg = (const float*)d_in[3];  // [D,1]
    const float* b_seg = (const float*)d_in[4];  // [D]
    const float* pe    = (const float*)d_in[5];  // [MAX_LEN,1,D]
    float* out         = (float*)d_out;          // [S,B,D]

    dim3 grid(S_DIM, B_DIM / B_PER_BLOCK);
    dim3 block(256);
    pe_fused_kernel<<<grid, block, 0, stream>>>(x, W_xy, b_xy, W_seg, b_seg, pe, out);
}